// Round 8
// baseline (331.728 us; speedup 1.0000x reference)
//
#include <hip/hip_runtime.h>
#include <math.h>

#define CIN  64
#define CI   16
#define HH   256
#define WWD  256
#define KS   7
#define STR  4
#define LH   64
#define LWD  64
#define LL   4096
#define DIN  784
#define DINP 896     // padded to multiple of 128 (agg N)
#define DKP  832     // DIN padded to multiple of 64 (fc K)
#define DOUT 196
#define DOUTP 256    // padded N for fc / K for score GEMM
#define NB   2
#define YP   258     // padded rows in bTp
#define XP   264     // padded cols in bTp

typedef __attribute__((ext_vector_type(8))) short bf16x8;
typedef __attribute__((ext_vector_type(4))) float f32x4;
typedef __attribute__((ext_vector_type(16))) float f32x16;
typedef __attribute__((ext_vector_type(8))) int i32x8;
typedef __attribute__((ext_vector_type(4))) int i32x4;

__device__ __forceinline__ unsigned short f2bf(float x) {
    unsigned int u = __float_as_uint(x);
    unsigned int r = (u + 0x7FFFu + ((u >> 16) & 1u)) >> 16;
    return (unsigned short)r;
}
__device__ __forceinline__ float bf2f(unsigned short h) {
    return __uint_as_float(((unsigned int)h) << 16);
}

__device__ __forceinline__ void stage16(const void* g, void* l) {
#if defined(__has_builtin)
#if __has_builtin(__builtin_amdgcn_global_load_lds)
    __builtin_amdgcn_global_load_lds(
        (const __attribute__((address_space(1))) unsigned int*)g,
        (__attribute__((address_space(3))) unsigned int*)l, 16, 0, 0);
    return;
#endif
#endif
    *(float4*)l = *(const float4*)g;
}

// ---- prep: b (fp32 NCHW) -> bTp bf16 [n][y+1][s=ci/8][x+4][j=ci%8], padded -
__global__ __launch_bounds__(256) void k_prep_b(const float* __restrict__ b,
                                                unsigned short* __restrict__ bTp) {
    int blk = blockIdx.x;            // n*YP*8 blocks
    int s = blk & 7; int yy = (blk >> 3) % YP; int n = blk / (8 * YP);
    int y = yy - 1;
    for (int xx = threadIdx.x; xx < XP; xx += 256) {
        int x = xx - 4;
        bool v = (y >= 0 && y < 256 && x >= 0 && x < 256);
        unsigned short h[8];
#pragma unroll
        for (int j = 0; j < 8; j++)
            h[j] = v ? f2bf(b[((size_t)(n * 64 + s * 8 + j) * 256 + y) * 256 + x]) : (unsigned short)0;
        *(uint4*)&bTp[((((size_t)n * YP + yy) * 8 + s) * XP + xx) * 8] = *(uint4*)h;
    }
}

// ---- prep: conv weights -> wbt[t][h][q][co32][j8] bf16 ---------------------
__global__ void k_prep_wb(const float* __restrict__ g_w, const float* __restrict__ th_w,
                          unsigned short* __restrict__ wbt) {
    int i = blockIdx.x * 256 + threadIdx.x;
    if (i >= 18432) return;
    int j = i & 7, co = (i >> 3) & 31, q = (i >> 8) & 3, h = (i >> 10) & 1, t = i >> 11;
    int ci = h * 32 + q * 8 + j;
    float v;
    if (co < 16) v = g_w[((size_t)co * 64 + ci) * 9 + t];
    else         v = (t == 4) ? th_w[(size_t)(co - 16) * 64 + ci] : 0.f;
    wbt[i] = f2bf(v);
}

// ---- prep: fc weights -> bf16 [f][256][832], zero-padded -------------------
__global__ void k_prep_fc(const float* __restrict__ fc1_w, const float* __restrict__ fc2_w,
                          unsigned short* __restrict__ fcwb) {
    int i = blockIdx.x * 256 + threadIdx.x;
    if (i >= 2 * DOUTP * DKP) return;
    int col = i % DKP; int row = (i / DKP) % DOUTP; int f = i / (DKP * DOUTP);
    float v = 0.f;
    if (row < DOUT && col < DIN) v = (f ? fc2_w : fc1_w)[row * DIN + col];
    fcwb[i] = f2bf(v);
}

// ---- MFMA implicit-GEMM conv: bx[n][y][x][co32] ----------------------------
__global__ __launch_bounds__(256) void k_convm(
        const unsigned short* __restrict__ bTp, const unsigned short* __restrict__ wbt,
        const float* __restrict__ g_b, const float* __restrict__ th_b,
        unsigned short* __restrict__ bx) {
    __shared__ unsigned short wb[18432];
    __shared__ unsigned short ti[8 * 3 * 68 * 8];
    int tid = threadIdx.x;
#pragma unroll
    for (int i = 0; i < 9; i++) {
        int c = i * 256 + tid;
        stage16(wbt + (size_t)c * 8, &wb[c * 8]);
    }
    int n = blockIdx.x >> 8, y = blockIdx.x & 255;
    int wave = tid >> 6, lane = tid & 63, lr = lane & 15, q = lane >> 4;
    int m0 = wave * 16;
    float bg = g_b[lr], bt = th_b[lr];
    for (int xs = 0; xs < 4; xs++) {
        __syncthreads();
        int x0 = xs * 64;
#pragma unroll
        for (int i = 0; i < 7; i++) {
            int c = i * 256 + tid;
            if (c < 1632) {
                int s = c / 204; int rem = c % 204; int r = rem / 68; int cc = rem % 68;
                const unsigned short* src =
                    bTp + ((((size_t)n * YP + y + r) * 8 + s) * XP + (x0 + 3 + cc)) * 8;
                stage16(src, &ti[c * 8]);
            }
        }
        __syncthreads();
        f32x4 a0 = {bg, bg, bg, bg}, a1 = {bt, bt, bt, bt};
#pragma unroll
        for (int t = 0; t < 9; t++) {
            int dy = t / 3, dx = t % 3;
#pragma unroll
            for (int h = 0; h < 2; h++) {
                int s = h * 4 + q;
                bf16x8 av = *(const bf16x8*)&ti[(((s * 3 + dy) * 68) + m0 + lr + dx) * 8];
                bf16x8 b0 = *(const bf16x8*)&wb[((((t * 2 + h) * 4 + q) * 32) + lr) * 8];
                bf16x8 b1 = *(const bf16x8*)&wb[((((t * 2 + h) * 4 + q) * 32) + 16 + lr) * 8];
                a0 = __builtin_amdgcn_mfma_f32_16x16x32_bf16(av, b0, a0, 0, 0, 0);
                a1 = __builtin_amdgcn_mfma_f32_16x16x32_bf16(av, b1, a1, 0, 0, 0);
            }
        }
        size_t pb = (((size_t)n * 256 + y) * 256 + x0 + m0 + q * 4);
#pragma unroll
        for (int r = 0; r < 4; r++) {
            bx[(pb + r) * 32 + lr]      = f2bf(a0[r]);
            bx[(pb + r) * 32 + 16 + lr] = f2bf(a1[r]);
        }
    }
}

// ---- thr: 7x7 stride-4 conv from bf16 bTp; wave per output, lane=(s,j)=ci --
__global__ __launch_bounds__(256) void k_thr(
        const unsigned short* __restrict__ bTp, const float* __restrict__ thr_w,
        const float* __restrict__ thr_b, float* __restrict__ thr) {
    __shared__ float w[64 * 49];
    int tid = threadIdx.x;
    for (int i = tid; i < 64 * 49; i += 256) w[i] = thr_w[i];
    __syncthreads();
    int wid = (blockIdx.x << 2) + (tid >> 6);
    int lane = tid & 63;
    int s = lane >> 3, j = lane & 7;
    int n = wid >> 12, l = wid & 4095;
    int lh = (l >> 6), lw = l & 63;
    const float* wl = w + (s * 8 + j) * 49;
    float acc = 0.f;
#pragma unroll
    for (int dy = 0; dy < 7; dy++) {
        int yy = lh * 4 + dy;
        if (yy >= YP) continue;
        const unsigned short* row = bTp + (((size_t)(n * YP + yy) * 8 + s) * XP) * 8;
#pragma unroll
        for (int dx = 0; dx < 7; dx++) {
            int xx = lw * 4 + dx + 3;
            acc = fmaf(bf2f(row[xx * 8 + j]), wl[dy * 7 + dx], acc);
        }
    }
#pragma unroll
    for (int off = 32; off > 0; off >>= 1) acc += __shfl_down(acc, off, 64);
    if (lane == 0) thr[wid] = acc + thr_b[0];
}

// ---- patches of bx(co<16) -> Pb bf16 [n][l][DKP], zero-padded --------------
__global__ void k_patchesA(const unsigned short* __restrict__ bx, unsigned short* __restrict__ Pb) {
    size_t e = (size_t)blockIdx.x * 256 + threadIdx.x;
    if (e >= (size_t)NB * LL * DKP) return;
    int d = (int)(e % DKP); size_t r = e / DKP;
    int l = (int)(r & 4095); int n = (int)(r >> 12);
    unsigned short v = 0;
    if (d < DIN) {
        int ci = d / 49; int t = d % 49; int dy = t / 7; int dx = t % 7;
        int y = (l >> 6) * 4 + dy - 1, x = (l & 63) * 4 + dx - 1;
        if (y >= 0 && y < 256 && x >= 0 && x < 256)
            v = bx[(((size_t)n * 256 + y) * 256 + x) * 32 + ci];
    }
    Pb[e] = v;
}

// ---- patches of bx(co>=16) -> piT8 fp8 e4m3 [n][d][l], d padded to DINP ----
__global__ void k_patchesT(const unsigned short* __restrict__ bx, unsigned char* __restrict__ piT8) {
    size_t e = (size_t)blockIdx.x * 256 + threadIdx.x;
    int l = (int)(e & 4095);
    int d = (int)((e >> 12) % DINP);
    int n = (int)(e / ((size_t)DINP * LL));
    float v = 0.f;
    if (d < DIN) {
        int ci = d / 49; int t = d % 49; int dy = t / 7; int dx = t % 7;
        int y = (l >> 6) * 4 + dy - 1, x = (l & 63) * 4 + dx - 1;
        if (y >= 0 && y < 256 && x >= 0 && x < 256)
            v = bf2f(bx[(((size_t)n * 256 + y) * 256 + x) * 32 + 16 + ci]);
    }
    int p = __builtin_amdgcn_cvt_pk_fp8_f32(v, 0.f, 0, false);
    piT8[e] = (unsigned char)(p & 0xFF);
}

// ---- MFMA GEMM (NT) bf16: MODE 1 bf16 out; MODE 2 fc epilogue --------------
template<int MODE>
__global__ __launch_bounds__(256) void k_gemm_nt(
        const unsigned short* __restrict__ A, const unsigned short* __restrict__ Bt,
        void* __restrict__ C, int lda, int ldb, int ldc, int K,
        size_t sA, size_t sB, size_t sC,
        const float* __restrict__ bias1, const float* __restrict__ bias2) {
    __shared__ unsigned short lA[128 * 64];
    __shared__ unsigned short lB[128 * 64];
    int tid = threadIdx.x;
    int wave = tid >> 6, lane = tid & 63;
    int lr = lane & 15, lq = lane >> 4;
    int wm = (wave >> 1) * 64, wn = (wave & 1) * 64;
    int i0 = blockIdx.x * 128, j0 = blockIdx.y * 128;
    int z = blockIdx.z;
    int az = (MODE == 2) ? (z >> 1) : z;
    int bz = (MODE == 2) ? (z & 1) : z;
    const unsigned short* Ab = A + (size_t)az * sA + (size_t)i0 * lda;
    const unsigned short* Bb = Bt + (size_t)bz * sB + (size_t)j0 * ldb;
    f32x4 acc[4][4] = {};
    for (int k0 = 0; k0 < K; k0 += 64) {
        __syncthreads();
#pragma unroll
        for (int it = 0; it < 4; it++) {
            int c = it * 256 + tid;
            int row = c >> 3, slot = c & 7;
            int col8 = slot ^ (row & 7);
            stage16(Ab + (size_t)row * lda + k0 + col8 * 8, &lA[c * 8]);
        }
#pragma unroll
        for (int it = 0; it < 4; it++) {
            int c = it * 256 + tid;
            int row = c >> 3, slot = c & 7;
            int col8 = slot ^ (row & 7);
            stage16(Bb + (size_t)row * ldb + k0 + col8 * 8, &lB[c * 8]);
        }
        __syncthreads();
#pragma unroll
        for (int ks = 0; ks < 2; ks++) {
            bf16x8 af[4], bfr[4];
#pragma unroll
            for (int t = 0; t < 4; t++) {
                int row = wm + t * 16 + lr;
                int slot = ks * 4 + lq;
                af[t] = *(const bf16x8*)&lA[row * 64 + (slot ^ (row & 7)) * 8];
            }
#pragma unroll
            for (int t = 0; t < 4; t++) {
                int row = wn + t * 16 + lr;
                int slot = ks * 4 + lq;
                bfr[t] = *(const bf16x8*)&lB[row * 64 + (slot ^ (row & 7)) * 8];
            }
#pragma unroll
            for (int mi = 0; mi < 4; mi++)
#pragma unroll
                for (int nj = 0; nj < 4; nj++)
                    acc[mi][nj] = __builtin_amdgcn_mfma_f32_16x16x32_bf16(
                        af[mi], bfr[nj], acc[mi][nj], 0, 0, 0);
        }
    }
    if (MODE == 1) {
        unsigned short* Cb = (unsigned short*)C + (size_t)z * sC;
#pragma unroll
        for (int mi = 0; mi < 4; mi++)
#pragma unroll
            for (int r = 0; r < 4; r++) {
                int row = i0 + wm + mi * 16 + lq * 4 + r;
#pragma unroll
                for (int nj = 0; nj < 4; nj++)
                    Cb[(size_t)row * ldc + j0 + wn + nj * 16 + lr] = f2bf(acc[mi][nj][r]);
            }
    } else {
        const float* biasp = bz ? bias2 : bias1;
        unsigned short* Cb = (unsigned short*)C + (size_t)z * sC;
#pragma unroll
        for (int mi = 0; mi < 4; mi++)
#pragma unroll
            for (int r = 0; r < 4; r++) {
                int row = i0 + wm + mi * 16 + lq * 4 + r;
#pragma unroll
                for (int nj = 0; nj < 4; nj++) {
                    int col = j0 + wn + nj * 16 + lr;
                    float bv = (col < DOUT) ? biasp[col] : 0.f;
                    float v = fmaxf(acc[mi][nj][r] + bv, 0.f);
                    Cb[(size_t)row * ldc + col] = f2bf(v);
                }
            }
    }
}

// ---- MX-fp8 MFMA GEMM (NT): agg = attn8 @ piT8^T, unit scales --------------
__global__ __launch_bounds__(256) void k_gemm_mx(
        const unsigned char* __restrict__ A, const unsigned char* __restrict__ Bt,
        unsigned short* __restrict__ C, int lda, int ldb, int ldc, int K,
        size_t sA, size_t sB, size_t sC) {
    __shared__ unsigned char lA[128 * 128];
    __shared__ unsigned char lB[128 * 128];
    int tid = threadIdx.x;
    int wave = tid >> 6, lane = tid & 63;
    int lr = lane & 31, hf = lane >> 5;
    int wm = (wave >> 1) * 64, wn = (wave & 1) * 64;
    int i0 = blockIdx.x * 128, j0 = blockIdx.y * 128;
    int z = blockIdx.z;
    const unsigned char* Ab = A + (size_t)z * sA + (size_t)i0 * lda;
    const unsigned char* Bb = Bt + (size_t)z * sB + (size_t)j0 * ldb;
    f32x16 acc[2][2] = {};
    for (int k0 = 0; k0 < K; k0 += 128) {
        __syncthreads();
#pragma unroll
        for (int it = 0; it < 4; it++) {
            int c = it * 256 + tid;
            int row = c >> 3, slot = c & 7;
            int col16 = slot ^ (row & 7);
            stage16(Ab + (size_t)row * lda + k0 + col16 * 16, &lA[c * 16]);
        }
#pragma unroll
        for (int it = 0; it < 4; it++) {
            int c = it * 256 + tid;
            int row = c >> 3, slot = c & 7;
            int col16 = slot ^ (row & 7);
            stage16(Bb + (size_t)row * ldb + k0 + col16 * 16, &lB[c * 16]);
        }
        __syncthreads();
#pragma unroll
        for (int kk = 0; kk < 2; kk++) {
            i32x8 af[2], bfv[2];
            int c0 = kk * 4 + hf * 2;
#pragma unroll
            for (int t = 0; t < 2; t++) {
                int row = wm + t * 32 + lr;
                i32x4 lo = *(const i32x4*)&lA[row * 128 + ((c0    ) ^ (row & 7)) * 16];
                i32x4 hi = *(const i32x4*)&lA[row * 128 + ((c0 + 1) ^ (row & 7)) * 16];
                af[t][0] = lo[0]; af[t][1] = lo[1]; af[t][2] = lo[2]; af[t][3] = lo[3];
                af[t][4] = hi[0]; af[t][5] = hi[1]; af[t][6] = hi[2]; af[t][7] = hi[3];
            }
#pragma unroll
            for (int t = 0; t < 2; t++) {
                int row = wn + t * 32 + lr;
                i32x4 lo = *(const i32x4*)&lB[row * 128 + ((c0    ) ^ (row & 7)) * 16];
                i32x4 hi = *(const i32x4*)&lB[row * 128 + ((c0 + 1) ^ (row & 7)) * 16];
                bfv[t][0] = lo[0]; bfv[t][1] = lo[1]; bfv[t][2] = lo[2]; bfv[t][3] = lo[3];
                bfv[t][4] = hi[0]; bfv[t][5] = hi[1]; bfv[t][6] = hi[2]; bfv[t][7] = hi[3];
            }
#pragma unroll
            for (int mi = 0; mi < 2; mi++)
#pragma unroll
                for (int nj = 0; nj < 2; nj++)
                    acc[mi][nj] = __builtin_amdgcn_mfma_scale_f32_32x32x64_f8f6f4(
                        af[mi], bfv[nj], acc[mi][nj],
                        0, 0, 0, 0x7F7F7F7F, 0, 0x7F7F7F7F);
        }
    }
    unsigned short* Cb = C + (size_t)z * sC;
#pragma unroll
    for (int mi = 0; mi < 2; mi++)
#pragma unroll
        for (int nj = 0; nj < 2; nj++)
#pragma unroll
            for (int reg = 0; reg < 16; reg++) {
                int row = i0 + wm + mi * 32 + (reg & 3) + 8 * (reg >> 2) + 4 * hf;
                int col = j0 + wn + nj * 32 + lr;
                Cb[(size_t)row * ldc + col] = f2bf(acc[mi][nj][reg]);
            }
}

// ---- fused masked-softmax: bf16 score row -> fp8 attn row (exp computed once)
__global__ __launch_bounds__(256) void k_softmax(
        const unsigned short* __restrict__ score, const float* __restrict__ thr,
        unsigned char* __restrict__ attn8) {
    __shared__ uint4 srow[512];             // 4096 bf16 raw
    __shared__ float se[4096];              // exp values, strided [i*512 + c]
    __shared__ float red[256], red2[256];
    int row = blockIdx.x, tid = threadIdx.x;
    const uint4* g4 = (const uint4*)(score + (size_t)row * LL);
    float t = thr[row];
    float mx = 0.f;
#pragma unroll
    for (int c = tid; c < 512; c += 256) {
        uint4 u = g4[c];
        srow[c] = u;
        unsigned int w[4] = {u.x, u.y, u.z, u.w};
#pragma unroll
        for (int qq = 0; qq < 4; qq++) {
            float v0 = __uint_as_float(w[qq] << 16);
            float v1 = __uint_as_float(w[qq] & 0xFFFF0000u);
            if (v0 >= t) mx = fmaxf(mx, v0);
            if (v1 >= t) mx = fmaxf(mx, v1);
        }
    }
    red[tid] = mx; __syncthreads();
    for (int st = 128; st > 0; st >>= 1) {
        if (tid < st) red[tid] = fmaxf(red[tid], red[tid + st]);
        __syncthreads();
    }
    float M = 10.f * fmaxf(red[0], 0.f);
    __syncthreads();
    float s2 = 0.f, n0 = 0.f;
#pragma unroll
    for (int c = tid; c < 512; c += 256) {
        uint4 u = srow[c];
        unsigned int w[4] = {u.x, u.y, u.z, u.w};
#pragma unroll
        for (int qq = 0; qq < 4; qq++) {
            float v0 = __uint_as_float(w[qq] << 16);
            float v1 = __uint_as_float(w[qq] & 0xFFFF0000u);
            float e0 = 0.f, e1 = 0.f;
            if (v0 >= t) { e0 = __expf(10.f * v0 - M); s2 += e0; } else n0 += 1.f;
            if (v1 >= t) { e1 = __expf(10.f * v1 - M); s2 += e1; } else n0 += 1.f;
            se[((2 * qq)     << 9) | c] = e0;
            se[((2 * qq + 1) << 9) | c] = e1;
        }
    }
    red[tid] = s2; red2[tid] = n0; __syncthreads();
    for (int st = 128; st > 0; st >>= 1) {
        if (tid < st) { red[tid] += red[tid + st]; red2[tid] += red2[tid + st]; }
        __syncthreads();
    }
    float S2 = red[0], N0 = red2[0];
    float iD = 1.f / (S2 + 1e-8f * (S2 + N0 * __expf(-M)));
#pragma unroll
    for (int c = tid; c < 512; c += 256) {
        float a[8];
#pragma unroll
        for (int i = 0; i < 8; i++) a[i] = se[(i << 9) | c] * iD;
        int d0 = __builtin_amdgcn_cvt_pk_fp8_f32(a[0], a[1], 0, false);
        d0     = __builtin_amdgcn_cvt_pk_fp8_f32(a[2], a[3], d0, true);
        int d1 = __builtin_amdgcn_cvt_pk_fp8_f32(a[4], a[5], 0, false);
        d1     = __builtin_amdgcn_cvt_pk_fp8_f32(a[6], a[7], d1, true);
        *(uint2*)&attn8[(size_t)row * LL + c * 8] = make_uint2((unsigned)d0, (unsigned)d1);
    }
}

// ---- fused fold + final: out = b(bf16 bTp) + (fold(aggb)/cnt) @ W_w^T + W_b
__global__ __launch_bounds__(256) void k_foldfinal(
        const unsigned short* __restrict__ aggb, const unsigned short* __restrict__ bTp,
        const float* __restrict__ W_w, const float* __restrict__ W_b,
        float* __restrict__ out) {
    int p = blockIdx.x * 256 + threadIdx.x;   // (n, y, x)
    int x = p & 255, y = (p >> 8) & 255, n = p >> 16;
    int yp = y + 1, xp = x + 1;
    int lh1 = yp >> 2; if (lh1 > 63) lh1 = 63;
    int lh0 = (yp >= 3) ? ((yp - 3) >> 2) : 0;
    int lw1 = xp >> 2; if (lw1 > 63) lw1 = 63;
    int lw0 = (xp >= 3) ? ((xp - 3) >> 2) : 0;
    const unsigned short* a0 = aggb + (size_t)n * LL * DINP;
    float icnt = 1.f / (float)((lh1 - lh0 + 1) * (lw1 - lw0 + 1));
    float zloc[16];
#pragma unroll
    for (int ci = 0; ci < 16; ci++) zloc[ci] = 0.f;
    for (int lh = lh0; lh <= lh1; lh++) {
        int dy = yp - 4 * lh;
        for (int lw = lw0; lw <= lw1; lw++) {
            int dx = xp - 4 * lw;
            const unsigned short* ap = a0 + (size_t)(lh * 64 + lw) * DINP + dy * 7 + dx;
#pragma unroll
            for (int ci = 0; ci < 16; ci++) zloc[ci] += bf2f(ap[ci * 49]);
        }
    }
#pragma unroll
    for (int ci = 0; ci < 16; ci++) zloc[ci] *= icnt;
    float* on = out + (size_t)n * 64 * 65536 + (y * 256 + x);
#pragma unroll
    for (int s = 0; s < 8; s++) {
        uint4 b8 = *(const uint4*)&bTp[((((size_t)n * YP + y + 1) * 8 + s) * XP + x + 4) * 8];
        unsigned int bw[4] = {b8.x, b8.y, b8.z, b8.w};
#pragma unroll
        for (int j = 0; j < 8; j++) {
            int co = s * 8 + j;
            float acc = W_b[co];                      // uniform -> s_load
#pragma unroll
            for (int ci = 0; ci < 16; ci++)
                acc = fmaf(zloc[ci], W_w[co * 16 + ci], acc);   // uniform weight -> s_load
            unsigned int hw = bw[j >> 1];
            float bres = __uint_as_float((j & 1) ? (hw & 0xFFFF0000u) : (hw << 16));
            on[(size_t)co * 65536] = bres + acc;
        }
    }
}

extern "C" void kernel_launch(void* const* d_in, const int* in_sizes, int n_in,
                              void* d_out, int out_size, void* d_ws, size_t ws_size,
                              hipStream_t stream) {
    const float* b     = (const float*)d_in[0];
    const float* g_w   = (const float*)d_in[1];
    const float* g_b   = (const float*)d_in[2];
    const float* th_w  = (const float*)d_in[3];
    const float* th_b  = (const float*)d_in[4];
    const float* W_w   = (const float*)d_in[5];
    const float* W_b   = (const float*)d_in[6];
    const float* fc1_w = (const float*)d_in[7];
    const float* fc1_b = (const float*)d_in[8];
    const float* fc2_w = (const float*)d_in[9];
    const float* fc2_b = (const float*)d_in[10];
    const float* thr_w = (const float*)d_in[11];
    const float* thr_b = (const float*)d_in[12];
    // d_in[13], d_in[14] (bias conv): constant along softmax axis -> cancels.
    float* out = (float*)d_out;

    float* ws = (float*)d_ws;
    size_t off = 0;
    auto alloc = [&](size_t nf) { float* p = ws + off; off += (nf + 63) & ~(size_t)63; return p; };
    unsigned short* aggb = (unsigned short*)alloc((size_t)NB * LL * DINP / 2);
    unsigned short* bTp  = (unsigned short*)alloc((size_t)NB * YP * 8 * XP * 8 / 2);
    unsigned short* bx   = (unsigned short*)alloc((size_t)NB * HH * WWD * 32 / 2);
    unsigned short* Pb   = (unsigned short*)alloc((size_t)NB * LL * DKP / 2);
    unsigned char*  piT8 = (unsigned char*)alloc((size_t)NB * DINP * LL / 4);
    unsigned short* fcout = (unsigned short*)alloc((size_t)NB * 2 * LL * DOUTP / 2);
    unsigned short* wbt  = (unsigned short*)alloc(18432 / 2);
    unsigned short* fcwb = (unsigned short*)alloc((size_t)2 * DOUTP * DKP / 2);
    float* thr  = alloc((size_t)NB * LL);
    unsigned short* score = (unsigned short*)alloc((size_t)NB * LL * LL / 2);
    unsigned char*  attn8 = (unsigned char*)alloc((size_t)NB * LL * LL / 4);

    k_prep_b<<<dim3(NB * YP * 8), 256, 0, stream>>>(b, bTp);
    k_prep_wb<<<dim3(72), 256, 0, stream>>>(g_w, th_w, wbt);
    k_prep_fc<<<dim3((2 * DOUTP * DKP + 255) / 256), 256, 0, stream>>>(fc1_w, fc2_w, fcwb);
    k_convm<<<dim3(NB * 256), 256, 0, stream>>>(bTp, wbt, g_b, th_b, bx);
    k_thr<<<dim3(2048), 256, 0, stream>>>(bTp, thr_w, thr_b, thr);
    k_patchesA<<<dim3((int)((size_t)NB * LL * DKP / 256)), 256, 0, stream>>>(bx, Pb);
    k_patchesT<<<dim3((int)((size_t)NB * DINP * LL / 256)), 256, 0, stream>>>(bx, piT8);
    // FC: wif/xif = relu(Pb @ fcwb^T + bias) -> fcout[z=n*2+f][4096][256] bf16
    k_gemm_nt<2><<<dim3(32, 2, 4), 256, 0, stream>>>(
        Pb, fcwb, (void*)fcout, DKP, DKP, DOUTP, DKP,
        (size_t)LL * DKP, (size_t)DOUTP * DKP, (size_t)LL * DOUTP, fc1_b, fc2_b);
    // score[l][m] = wif[l].xif[m]  (bf16 out)
    k_gemm_nt<1><<<dim3(32, 32, NB), 256, 0, stream>>>(
        fcout, fcout + (size_t)LL * DOUTP, (void*)score, DOUTP, DOUTP, LL, DOUTP,
        (size_t)2 * LL * DOUTP, (size_t)2 * LL * DOUTP, (size_t)LL * LL, nullptr, nullptr);
    k_softmax<<<dim3(NB * LL), 256, 0, stream>>>(score, thr, attn8);
    // agg[l][d] = sum_m attn8[l][m] * piT8[d][m]  (MX fp8, unit scale, bf16 out)
    k_gemm_mx<<<dim3(32, DINP / 128, NB), 256, 0, stream>>>(
        attn8, piT8, aggb, LL, LL, DINP, LL,
        (size_t)LL * LL, (size_t)DINP * LL, (size_t)LL * DINP);
    k_foldfinal<<<dim3(512), 256, 0, stream>>>(aggb, bTp, W_w, W_b, out);
}